// Round 7
// baseline (2755.298 us; speedup 1.0000x reference)
//
#include <hip/hip_runtime.h>
#include <math.h>

// Problem constants
constexpr int kB    = 2048;
constexpr int kA    = 8;
constexpr int kEin  = 64;
constexpr int kEout = 256;
constexpr int kH    = 1024;
constexpr int kV    = 1024;
constexpr int kL    = 16;
constexpr int kKin  = kA * kEin;      // 512
constexpr int kKg   = kEout + kH;     // 1280
constexpr float kInvLo = 1.0f / 2048.0f;

using half8 = __attribute__((ext_vector_type(8))) _Float16;
using half4 = __attribute__((ext_vector_type(4))) _Float16;
using f32x4 = __attribute__((ext_vector_type(4))) float;

// async global->LDS, 16B per lane; lds base must be wave-uniform, dest = base + lane*16
#define GLL16(g, l) __builtin_amdgcn_global_load_lds(                        \
    (const __attribute__((address_space(1))) void*)(g),                      \
    (__attribute__((address_space(3))) void*)(l), 16, 0, 0)
#define SCHEDB() __builtin_amdgcn_sched_barrier(0)

__device__ __forceinline__ float sigm(float x) { return 1.0f / (1.0f + expf(-x)); }

// fp32 -> fp16 hi + fp16 lo (x ~= hi + lo/2048), ~22 significant bits
struct HL { _Float16 hi, lo; };
__device__ __forceinline__ HL split2v(float x) {
  HL r;
  r.hi = (_Float16)x;
  r.lo = (_Float16)((x - (float)r.hi) * 2048.0f);
  return r;
}

// ---------------------------------------------------------------- init state
__global__ __launch_bounds__(256) void init_state(float* __restrict__ c,
                                                  _Float16* __restrict__ emb_hi,
                                                  _Float16* __restrict__ emb_lo,
                                                  const float* __restrict__ sos) {
  int i = blockIdx.x * 256 + threadIdx.x;
  c[i] = 0.0f;
  if (i < kB * kEout) {
    HL s = split2v(sos[i & (kEout - 1)]);
    emb_hi[i] = s.hi; emb_lo[i] = s.lo;
  }
}

// -------------------------------------------------- plain fp32 -> hi/lo split
__global__ __launch_bounds__(256) void split_plain(const float* __restrict__ src,
                                                   _Float16* __restrict__ hi,
                                                   _Float16* __restrict__ lo,
                                                   int n4) {
  int i = blockIdx.x * 256 + threadIdx.x;
  if (i >= n4) return;
  float4 v = ((const float4*)src)[i];
  half4 h, l;
  HL s0 = split2v(v.x), s1 = split2v(v.y), s2 = split2v(v.z), s3 = split2v(v.w);
  h.x = s0.hi; l.x = s0.lo; h.y = s1.hi; l.y = s1.lo;
  h.z = s2.hi; l.z = s2.lo; h.w = s3.hi; l.w = s3.lo;
  *(half4*)(hi + (size_t)i * 4) = h;
  *(half4*)(lo + (size_t)i * 4) = l;
}

// ------------------------- gates weights: concat [W_ih|W_hh], gate-permute, split
// output row n <-> gate=(n>>4)&3, j=((n>>6)<<4)|(n&15); source row = gate*1024+j
__global__ __launch_bounds__(320) void split_gates_w(const float* __restrict__ W_ih,
                                                     const float* __restrict__ W_hh,
                                                     _Float16* __restrict__ hi,
                                                     _Float16* __restrict__ lo) {
  const int n  = blockIdx.x;
  const int k4 = threadIdx.x * 4;
  const int g  = (n >> 4) & 3;
  const int j  = ((n >> 6) << 4) | (n & 15);
  const int src = g * kH + j;
  float4 v = (k4 < kEout) ? *(const float4*)&W_ih[(size_t)src * kEout + k4]
                          : *(const float4*)&W_hh[(size_t)src * kH + (k4 - kEout)];
  half4 h, l;
  HL s0 = split2v(v.x), s1 = split2v(v.y), s2 = split2v(v.z), s3 = split2v(v.w);
  h.x = s0.hi; l.x = s0.lo; h.y = s1.hi; l.y = s1.lo;
  h.z = s2.hi; l.z = s2.lo; h.w = s3.hi; l.w = s3.lo;
  *(half4*)(hi + (size_t)n * kKg + k4) = h;
  *(half4*)(lo + (size_t)n * kKg + k4) = l;
}

// ------------------------------------------------------- h0 = embed @ W_in^T
// fp32 vector GEMM (runs once); epilogue emits split h0
__global__ __launch_bounds__(256) void h0_gemm(const int* __restrict__ x,
                                               const float* __restrict__ in_emb,
                                               const float* __restrict__ W_in,
                                               const float* __restrict__ b_in,
                                               _Float16* __restrict__ h_hi,
                                               _Float16* __restrict__ h_lo) {
  __shared__ float As[16][128];
  __shared__ float Bs[16][128];
  const int t  = threadIdx.x;
  const int tx = t & 15, ty = t >> 4;
  const int r  = t >> 1;
  const int kc = (t & 1) * 8;
  const int m0 = blockIdx.x * 128;
  const int n0 = blockIdx.y * 128;
  float acc[8][8] = {};
  for (int k0 = 0; k0 < kKin; k0 += 16) {
    const int kk   = k0 + kc;
    const int attr = kk >> 6;
    const int e    = kk & 63;
    const int idx  = x[(m0 + r) * kA + attr];
    const float* pa = in_emb + (size_t)idx * kEin + e;
    float4 a0 = *(const float4*)pa;
    float4 a1 = *(const float4*)(pa + 4);
    const float* pb = W_in + (size_t)(n0 + r) * kKin + kk;
    float4 b0 = *(const float4*)pb;
    float4 b1 = *(const float4*)(pb + 4);
    __syncthreads();
    As[kc+0][r]=a0.x; As[kc+1][r]=a0.y; As[kc+2][r]=a0.z; As[kc+3][r]=a0.w;
    As[kc+4][r]=a1.x; As[kc+5][r]=a1.y; As[kc+6][r]=a1.z; As[kc+7][r]=a1.w;
    Bs[kc+0][r]=b0.x; Bs[kc+1][r]=b0.y; Bs[kc+2][r]=b0.z; Bs[kc+3][r]=b0.w;
    Bs[kc+4][r]=b1.x; Bs[kc+5][r]=b1.y; Bs[kc+6][r]=b1.z; Bs[kc+7][r]=b1.w;
    __syncthreads();
#pragma unroll
    for (int k = 0; k < 16; ++k) {
      float a[8], b[8];
      *(float4*)&a[0] = *(const float4*)&As[k][ty*8];
      *(float4*)&a[4] = *(const float4*)&As[k][ty*8+4];
      *(float4*)&b[0] = *(const float4*)&Bs[k][tx*8];
      *(float4*)&b[4] = *(const float4*)&Bs[k][tx*8+4];
#pragma unroll
      for (int i = 0; i < 8; ++i)
#pragma unroll
        for (int j = 0; j < 8; ++j)
          acc[i][j] = fmaf(a[i], b[j], acc[i][j]);
    }
  }
#pragma unroll
  for (int i = 0; i < 8; ++i) {
    const int gm = m0 + ty*8 + i;
#pragma unroll
    for (int j = 0; j < 8; ++j) {
      const int gn = n0 + tx*8 + j;
      HL s = split2v(acc[i][j] + b_in[gn]);
      h_hi[(size_t)gm * kH + gn] = s.hi;
      h_lo[(size_t)gm * kH + gn] = s.lo;
    }
  }
}

// --------------------- gates GEMM (fp16x2 MFMA, 3 passes) + fused LSTM pointwise
// Occupancy-first structure: 128x64 tile, 4 waves stacked in M (wave = 32x64,
// mf 0..1, nf 0..3 = 4 gates). Grid 16x64 = 1024 blocks = 4 blocks/CU =
// 16 waves/CU = 4 waves/SIMD -> TLP hides the staging drain (single-buffer,
// plain 2-barrier loop). XCD-bijective swizzle: each XCD gets 8 weight panels
// x all 16 M-blocks (weights fetched ~once per XCD).
__global__ __launch_bounds__(256, 4) void gates_lstm_mfma(
    const _Float16* __restrict__ emb_hi, const _Float16* __restrict__ emb_lo,
    const _Float16* __restrict__ h_hi,   const _Float16* __restrict__ h_lo,
    const _Float16* __restrict__ Wg_hi,  const _Float16* __restrict__ Wg_lo,
    const float* __restrict__ b_ih, const float* __restrict__ b_hh,
    float* __restrict__ c,
    _Float16* __restrict__ ho_hi, _Float16* __restrict__ ho_lo) {
  __shared__ __align__(16) _Float16 Ah[4][128][8], Al[4][128][8],
                                    Bh[4][64][8],  Bl[4][64][8];   // 24 KB
  const int t    = threadIdx.x;
  const int lin  = blockIdx.y * 16 + blockIdx.x;       // dispatch-linear
  const int sw   = (lin & 7) * 128 + (lin >> 3);       // bijective (1024=8*128)
  const int m0   = (sw & 15) * 128;
  const int by   = sw >> 4;                            // 0..63
  const int n0   = by * 64;
  const int lane = t & 63, wid = t >> 6;
  const int lc   = lane & 15, lg = lane >> 4;

  auto stage = [&](int k0) {                 // 6 vmem/thread; wave wid = kchunk wid
    const int k = k0 + wid * 8;
    const _Float16 *pa1h, *pa1l;
    if (k < kEout) {
      const size_t o = (size_t)(m0 + lane) * kEout + k;
      pa1h = emb_hi + o; pa1l = emb_lo + o;
      // rows +64
      GLL16(pa1h,                 &Ah[wid][0][0]);
      GLL16(emb_hi + o + (size_t)64 * kEout, &Ah[wid][64][0]);
      GLL16(pa1l,                 &Al[wid][0][0]);
      GLL16(emb_lo + o + (size_t)64 * kEout, &Al[wid][64][0]);
    } else {
      const size_t o = (size_t)(m0 + lane) * kH + (k - kEout);
      pa1h = h_hi + o; pa1l = h_lo + o;
      GLL16(pa1h,                 &Ah[wid][0][0]);
      GLL16(h_hi + o + (size_t)64 * kH, &Ah[wid][64][0]);
      GLL16(pa1l,                 &Al[wid][0][0]);
      GLL16(h_lo + o + (size_t)64 * kH, &Al[wid][64][0]);
    }
    const size_t ob = (size_t)(n0 + lane) * kKg + k;
    GLL16(Wg_hi + ob, &Bh[wid][0][0]);
    GLL16(Wg_lo + ob, &Bl[wid][0][0]);
  };

  f32x4 acc1[2][4] = {}; f32x4 acc2[2][4] = {};
  constexpr int NK = kKg / 32;                 // 40
  for (int ks = 0; ks < NK; ++ks) {
    stage(ks * 32);
    __syncthreads();                           // vmcnt(0): tile in LDS
    half8 ah[2], al[2];
#pragma unroll
    for (int mf = 0; mf < 2; ++mf) {
      ah[mf] = *(const half8*)&Ah[lg][wid*32 + mf*16 + lc][0];
      al[mf] = *(const half8*)&Al[lg][wid*32 + mf*16 + lc][0];
    }
#pragma unroll
    for (int nf = 0; nf < 4; ++nf) {
      const half8 bh = *(const half8*)&Bh[lg][nf*16 + lc][0];
      const half8 bl = *(const half8*)&Bl[lg][nf*16 + lc][0];
#pragma unroll
      for (int mf = 0; mf < 2; ++mf) {
        acc1[mf][nf] = __builtin_amdgcn_mfma_f32_16x16x32_f16(ah[mf], bh, acc1[mf][nf], 0, 0, 0);
        acc2[mf][nf] = __builtin_amdgcn_mfma_f32_16x16x32_f16(ah[mf], bl, acc2[mf][nf], 0, 0, 0);
        acc2[mf][nf] = __builtin_amdgcn_mfma_f32_16x16x32_f16(al[mf], bh, acc2[mf][nf], 0, 0, 0);
      }
    }
    __syncthreads();                           // frag reads done -> buffer reusable
  }
  // epilogue: j = by*16 + lc; gates nf = 0..3 (i,f,g,o); rows wid*32 span
  const int j = by * 16 + lc;
  float bb[4];
#pragma unroll
  for (int nf = 0; nf < 4; ++nf) bb[nf] = b_ih[nf * kH + j] + b_hh[nf * kH + j];
#pragma unroll
  for (int mf = 0; mf < 2; ++mf)
#pragma unroll
    for (int reg = 0; reg < 4; ++reg) {
      const int m = m0 + wid * 32 + mf * 16 + lg * 4 + reg;
      const size_t off = (size_t)m * kH + j;
      const float vi = acc1[mf][0][reg] + acc2[mf][0][reg] * kInvLo + bb[0];
      const float vf = acc1[mf][1][reg] + acc2[mf][1][reg] * kInvLo + bb[1];
      const float vg = acc1[mf][2][reg] + acc2[mf][2][reg] * kInvLo + bb[2];
      const float vo = acc1[mf][3][reg] + acc2[mf][3][reg] * kInvLo + bb[3];
      const float cn = sigm(vf) * c[off] + sigm(vi) * tanhf(vg);
      const float hn = sigm(vo) * tanhf(cn);
      c[off] = cn;
      HL s = split2v(hn);
      ho_hi[off] = s.hi; ho_lo[off] = s.lo;
    }
}

// ----------------------------- logits = h @ W_out^T + b (fp16x2 MFMA, 3 passes)
// 64x64 tile, 4 waves (2x2), wave 32x32. Depth-2 counted-vmcnt pipeline;
// staging split by role (waves 0,1 -> A; 2,3 -> B), 4 vmem ops per wave.
__global__ __launch_bounds__(256, 2) void logits_mfma(
    const _Float16* __restrict__ h_hi, const _Float16* __restrict__ h_lo,
    const _Float16* __restrict__ Wo_hi, const _Float16* __restrict__ Wo_lo,
    const float* __restrict__ b_out, float* __restrict__ out) {
  __shared__ __align__(16) _Float16 Ah[2][4][64][8], Al[2][4][64][8],
                                    Bh[2][4][64][8], Bl[2][4][64][8];
  const int t    = threadIdx.x;
  const int m0   = blockIdx.x * 64, n0 = blockIdx.y * 64;
  const int lane = t & 63, wid = t >> 6;
  const int lc   = lane & 15, lg = lane >> 4;
  const int wr   = wid >> 1, wc = wid & 1;    // wave tile 32x32
  const int isB  = wid >> 1;                  // staging role
  const int kq   = (wid & 1) * 2;             // kchunk base

  auto stage = [&](int p, int k0) {           // 4 vmem ops per wave
    if (isB == 0) {
      const size_t o = (size_t)(m0 + lane) * kH + k0 + kq * 8;
      GLL16(h_hi + o,      &Ah[p][kq  ][0][0]);
      GLL16(h_hi + o + 8,  &Ah[p][kq+1][0][0]);
      GLL16(h_lo + o,      &Al[p][kq  ][0][0]);
      GLL16(h_lo + o + 8,  &Al[p][kq+1][0][0]);
    } else {
      const size_t o = (size_t)(n0 + lane) * kH + k0 + kq * 8;
      GLL16(Wo_hi + o,     &Bh[p][kq  ][0][0]);
      GLL16(Wo_hi + o + 8, &Bh[p][kq+1][0][0]);
      GLL16(Wo_lo + o,     &Bl[p][kq  ][0][0]);
      GLL16(Wo_lo + o + 8, &Bl[p][kq+1][0][0]);
    }
  };

  f32x4 acc1[2][2] = {}; f32x4 acc2[2][2] = {};
  constexpr int NK = kH / 32;                 // 32
  stage(0, 0);
  for (int ks = 0; ks < NK; ++ks) {
    const int cur = ks & 1;
    if (ks + 1 < NK) {
      stage(cur ^ 1, (ks + 1) * 32);
      SCHEDB();
      asm volatile("s_waitcnt vmcnt(4)");
    } else {
      SCHEDB();
      asm volatile("s_waitcnt vmcnt(0)");
    }
    SCHEDB();
    __builtin_amdgcn_s_barrier();
    SCHEDB();
    half8 ah[2], al[2], bh[2], bl[2];
#pragma unroll
    for (int mf = 0; mf < 2; ++mf) {
      ah[mf] = *(const half8*)&Ah[cur][lg][wr*32 + mf*16 + lc][0];
      al[mf] = *(const half8*)&Al[cur][lg][wr*32 + mf*16 + lc][0];
    }
#pragma unroll
    for (int nf = 0; nf < 2; ++nf) {
      bh[nf] = *(const half8*)&Bh[cur][lg][wc*32 + nf*16 + lc][0];
      bl[nf] = *(const half8*)&Bl[cur][lg][wc*32 + nf*16 + lc][0];
    }
#pragma unroll
    for (int mf = 0; mf < 2; ++mf)
#pragma unroll
      for (int nf = 0; nf < 2; ++nf) {
        acc1[mf][nf] = __builtin_amdgcn_mfma_f32_16x16x32_f16(ah[mf], bh[nf], acc1[mf][nf], 0, 0, 0);
        acc2[mf][nf] = __builtin_amdgcn_mfma_f32_16x16x32_f16(ah[mf], bl[nf], acc2[mf][nf], 0, 0, 0);
        acc2[mf][nf] = __builtin_amdgcn_mfma_f32_16x16x32_f16(al[mf], bh[nf], acc2[mf][nf], 0, 0, 0);
      }
    SCHEDB();
    __builtin_amdgcn_s_barrier();
  }
#pragma unroll
  for (int mf = 0; mf < 2; ++mf)
#pragma unroll
    for (int reg = 0; reg < 4; ++reg) {
      const int m = m0 + wr*32 + mf * 16 + lg * 4 + reg;
#pragma unroll
      for (int nf = 0; nf < 2; ++nf) {
        const int n = n0 + wc*32 + nf * 16 + lc;
        out[(size_t)m * (kL * kV) + n] = acc1[mf][nf][reg] + acc2[mf][nf][reg] * kInvLo + b_out[n];
      }
    }
}

// --------------------------------- argmax (first-max) + seq write + emb gather
__global__ __launch_bounds__(256) void argmax_gather(const float* __restrict__ logits_t,
                                                     float* __restrict__ seq,
                                                     const _Float16* __restrict__ oemb_hi,
                                                     const _Float16* __restrict__ oemb_lo,
                                                     _Float16* __restrict__ emb_hi,
                                                     _Float16* __restrict__ emb_lo,
                                                     int t) {
  const int lane = threadIdx.x & 63;
  const int wv   = threadIdx.x >> 6;
  const int b    = blockIdx.x * 4 + wv;
  const float* row = logits_t + (size_t)b * (kL * kV);
  float m = -3.4e38f;
  int  mi = 0;
#pragma unroll
  for (int jr = 0; jr < kV / 64; ++jr) {
    const int idx = jr * 64 + lane;
    const float v = row[idx];
    if (v > m) { m = v; mi = idx; }
  }
#pragma unroll
  for (int off = 32; off > 0; off >>= 1) {
    const float om = __shfl_down(m, off);
    const int   oi = __shfl_down(mi, off);
    if (om > m || (om == m && oi < mi)) { m = om; mi = oi; }
  }
  mi = __shfl(mi, 0);
  if (lane == 0) seq[(size_t)b * kL + t] = (float)mi;
  const half4 eh = *(const half4*)&oemb_hi[(size_t)mi * kEout + lane * 4];
  const half4 el = *(const half4*)&oemb_lo[(size_t)mi * kEout + lane * 4];
  *(half4*)&emb_hi[(size_t)b * kEout + lane * 4] = eh;
  *(half4*)&emb_lo[(size_t)b * kEout + lane * 4] = el;
}

// ---------------------------------------------------------------------------
extern "C" void kernel_launch(void* const* d_in, const int* in_sizes, int n_in,
                              void* d_out, int out_size, void* d_ws, size_t ws_size,
                              hipStream_t stream) {
  const int*   x       = (const int*)d_in[0];
  const float* in_emb  = (const float*)d_in[1];
  const float* out_emb = (const float*)d_in[2];
  const float* W_in    = (const float*)d_in[3];
  const float* b_in    = (const float*)d_in[4];
  const float* W_ih    = (const float*)d_in[5];
  const float* b_ih    = (const float*)d_in[6];
  const float* W_hh    = (const float*)d_in[7];
  const float* b_hh    = (const float*)d_in[8];
  const float* W_out   = (const float*)d_in[9];
  const float* b_out   = (const float*)d_in[10];
  const float* sos     = (const float*)d_in[11];

  // workspace layout
  float* cb = (float*)d_ws;                            // [B,H] fp32 cell state
  _Float16* hp = (_Float16*)(cb + (size_t)kB * kH);
  const size_t nBH = (size_t)kB * kH;                  // 2097152
  _Float16* hA_hi  = hp;            _Float16* hA_lo  = hp + nBH;
  _Float16* hB_hi  = hp + 2*nBH;    _Float16* hB_lo  = hp + 3*nBH;
  _Float16* emb_hi = hp + 4*nBH;    _Float16* emb_lo = emb_hi + (size_t)kB*kEout;
  _Float16* Wg_hi  = emb_lo + (size_t)kB*kEout;
  _Float16* Wg_lo  = Wg_hi + (size_t)4*kH*kKg;         // 5242880 each
  _Float16* Wo_hi  = Wg_lo + (size_t)4*kH*kKg;
  _Float16* Wo_lo  = Wo_hi + (size_t)kV*kH;
  _Float16* oe_hi  = Wo_lo + (size_t)kV*kH;
  _Float16* oe_lo  = oe_hi + (size_t)kV*kEout;

  float* seq    = (float*)d_out;                       // [B,L]
  float* logits = seq + (size_t)kB * kL;               // [B,L,V]

  init_state<<<(kB * kH) / 256, 256, 0, stream>>>(cb, emb_hi, emb_lo, sos);
  split_gates_w<<<4 * kH, 320, 0, stream>>>(W_ih, W_hh, Wg_hi, Wg_lo);
  split_plain<<<(kV * kH / 4) / 256, 256, 0, stream>>>(W_out, Wo_hi, Wo_lo, kV * kH / 4);
  split_plain<<<(kV * kEout / 4) / 256, 256, 0, stream>>>(out_emb, oe_hi, oe_lo, kV * kEout / 4);
  h0_gemm<<<dim3(kB / 128, kH / 128), 256, 0, stream>>>(x, in_emb, W_in, b_in, hA_hi, hA_lo);

  for (int t = 0; t < kL; ++t) {
    const _Float16* hi_h = (t & 1) ? hB_hi : hA_hi;
    const _Float16* hi_l = (t & 1) ? hB_lo : hA_lo;
    _Float16* ho_h = (t & 1) ? hA_hi : hB_hi;
    _Float16* ho_l = (t & 1) ? hA_lo : hB_lo;
    gates_lstm_mfma<<<dim3(16, 64), 256, 0, stream>>>(
        emb_hi, emb_lo, hi_h, hi_l, Wg_hi, Wg_lo, b_ih, b_hh, cb, ho_h, ho_l);
    logits_mfma<<<dim3(kB / 64, kV / 64), 256, 0, stream>>>(
        ho_h, ho_l, Wo_hi, Wo_lo, b_out, logits + (size_t)t * kV);
    argmax_gather<<<kB / 4, 256, 0, stream>>>(logits + (size_t)t * kV, seq,
                                              oe_hi, oe_lo, emb_hi, emb_lo, t);
  }
}

// Round 8
// 2694.012 us; speedup vs baseline: 1.0227x; 1.0227x over previous
//
#include <hip/hip_runtime.h>
#include <math.h>

// Problem constants
constexpr int kB    = 2048;
constexpr int kA    = 8;
constexpr int kEin  = 64;
constexpr int kEout = 256;
constexpr int kH    = 1024;
constexpr int kV    = 1024;
constexpr int kL    = 16;
constexpr int kKin  = kA * kEin;      // 512
constexpr int kKg   = kEout + kH;     // 1280
constexpr float kInvLo = 1.0f / 2048.0f;

using half8 = __attribute__((ext_vector_type(8))) _Float16;
using half4 = __attribute__((ext_vector_type(4))) _Float16;
using f32x4 = __attribute__((ext_vector_type(4))) float;

// async global->LDS, 16B per lane; lds base must be wave-uniform, dest = base + lane*16
#define GLL16(g, l) __builtin_amdgcn_global_load_lds(                        \
    (const __attribute__((address_space(1))) void*)(g),                      \
    (__attribute__((address_space(3))) void*)(l), 16, 0, 0)
#define SCHEDB() __builtin_amdgcn_sched_barrier(0)

__device__ __forceinline__ float sigm(float x) { return 1.0f / (1.0f + expf(-x)); }

// fp32 -> fp16 hi + fp16 lo (x ~= hi + lo/2048), ~22 significant bits
struct HL { _Float16 hi, lo; };
__device__ __forceinline__ HL split2v(float x) {
  HL r;
  r.hi = (_Float16)x;
  r.lo = (_Float16)((x - (float)r.hi) * 2048.0f);
  return r;
}

// ---------------------------------------------------------------- init state
__global__ __launch_bounds__(256) void init_state(float* __restrict__ c,
                                                  _Float16* __restrict__ emb_hi,
                                                  _Float16* __restrict__ emb_lo,
                                                  const float* __restrict__ sos) {
  int i = blockIdx.x * 256 + threadIdx.x;
  c[i] = 0.0f;
  if (i < kB * kEout) {
    HL s = split2v(sos[i & (kEout - 1)]);
    emb_hi[i] = s.hi; emb_lo[i] = s.lo;
  }
}

// -------------------------------------------------- plain fp32 -> hi/lo split
__global__ __launch_bounds__(256) void split_plain(const float* __restrict__ src,
                                                   _Float16* __restrict__ hi,
                                                   _Float16* __restrict__ lo,
                                                   int n4) {
  int i = blockIdx.x * 256 + threadIdx.x;
  if (i >= n4) return;
  float4 v = ((const float4*)src)[i];
  half4 h, l;
  HL s0 = split2v(v.x), s1 = split2v(v.y), s2 = split2v(v.z), s3 = split2v(v.w);
  h.x = s0.hi; l.x = s0.lo; h.y = s1.hi; l.y = s1.lo;
  h.z = s2.hi; l.z = s2.lo; h.w = s3.hi; l.w = s3.lo;
  *(half4*)(hi + (size_t)i * 4) = h;
  *(half4*)(lo + (size_t)i * 4) = l;
}

// ------------------------- gates weights: concat [W_ih|W_hh], gate-permute, split
// output row n <-> gate=(n>>4)&3, j=((n>>6)<<4)|(n&15); source row = gate*1024+j
__global__ __launch_bounds__(320) void split_gates_w(const float* __restrict__ W_ih,
                                                     const float* __restrict__ W_hh,
                                                     _Float16* __restrict__ hi,
                                                     _Float16* __restrict__ lo) {
  const int n  = blockIdx.x;
  const int k4 = threadIdx.x * 4;
  const int g  = (n >> 4) & 3;
  const int j  = ((n >> 6) << 4) | (n & 15);
  const int src = g * kH + j;
  float4 v = (k4 < kEout) ? *(const float4*)&W_ih[(size_t)src * kEout + k4]
                          : *(const float4*)&W_hh[(size_t)src * kH + (k4 - kEout)];
  half4 h, l;
  HL s0 = split2v(v.x), s1 = split2v(v.y), s2 = split2v(v.z), s3 = split2v(v.w);
  h.x = s0.hi; l.x = s0.lo; h.y = s1.hi; l.y = s1.lo;
  h.z = s2.hi; l.z = s2.lo; h.w = s3.hi; l.w = s3.lo;
  *(half4*)(hi + (size_t)n * kKg + k4) = h;
  *(half4*)(lo + (size_t)n * kKg + k4) = l;
}

// ------------------------------------------------------- h0 = embed @ W_in^T
// fp32 vector GEMM (runs once); epilogue emits split h0
__global__ __launch_bounds__(256) void h0_gemm(const int* __restrict__ x,
                                               const float* __restrict__ in_emb,
                                               const float* __restrict__ W_in,
                                               const float* __restrict__ b_in,
                                               _Float16* __restrict__ h_hi,
                                               _Float16* __restrict__ h_lo) {
  __shared__ float As[16][128];
  __shared__ float Bs[16][128];
  const int t  = threadIdx.x;
  const int tx = t & 15, ty = t >> 4;
  const int r  = t >> 1;
  const int kc = (t & 1) * 8;
  const int m0 = blockIdx.x * 128;
  const int n0 = blockIdx.y * 128;
  float acc[8][8] = {};
  for (int k0 = 0; k0 < kKin; k0 += 16) {
    const int kk   = k0 + kc;
    const int attr = kk >> 6;
    const int e    = kk & 63;
    const int idx  = x[(m0 + r) * kA + attr];
    const float* pa = in_emb + (size_t)idx * kEin + e;
    float4 a0 = *(const float4*)pa;
    float4 a1 = *(const float4*)(pa + 4);
    const float* pb = W_in + (size_t)(n0 + r) * kKin + kk;
    float4 b0 = *(const float4*)pb;
    float4 b1 = *(const float4*)(pb + 4);
    __syncthreads();
    As[kc+0][r]=a0.x; As[kc+1][r]=a0.y; As[kc+2][r]=a0.z; As[kc+3][r]=a0.w;
    As[kc+4][r]=a1.x; As[kc+5][r]=a1.y; As[kc+6][r]=a1.z; As[kc+7][r]=a1.w;
    Bs[kc+0][r]=b0.x; Bs[kc+1][r]=b0.y; Bs[kc+2][r]=b0.z; Bs[kc+3][r]=b0.w;
    Bs[kc+4][r]=b1.x; Bs[kc+5][r]=b1.y; Bs[kc+6][r]=b1.z; Bs[kc+7][r]=b1.w;
    __syncthreads();
#pragma unroll
    for (int k = 0; k < 16; ++k) {
      float a[8], b[8];
      *(float4*)&a[0] = *(const float4*)&As[k][ty*8];
      *(float4*)&a[4] = *(const float4*)&As[k][ty*8+4];
      *(float4*)&b[0] = *(const float4*)&Bs[k][tx*8];
      *(float4*)&b[4] = *(const float4*)&Bs[k][tx*8+4];
#pragma unroll
      for (int i = 0; i < 8; ++i)
#pragma unroll
        for (int j = 0; j < 8; ++j)
          acc[i][j] = fmaf(a[i], b[j], acc[i][j]);
    }
  }
#pragma unroll
  for (int i = 0; i < 8; ++i) {
    const int gm = m0 + ty*8 + i;
#pragma unroll
    for (int j = 0; j < 8; ++j) {
      const int gn = n0 + tx*8 + j;
      HL s = split2v(acc[i][j] + b_in[gn]);
      h_hi[(size_t)gm * kH + gn] = s.hi;
      h_lo[(size_t)gm * kH + gn] = s.lo;
    }
  }
}

// --------------------- gates GEMM (fp16x2 MFMA, 3 passes) + fused LSTM pointwise
// 128x128 tile (round-4 traffic-optimal mapping) but 512 threads = 8 waves:
// 16 waves/CU = 4 waves/SIMD for latency hiding. Wave grid 4M x 2N, wave tile
// 32x64 (2 mf x 4 nf; nf = gate). Per-thread staging: 4 global_load_lds.
// VGPR must stay <=128 (launch_bounds 512,4) or 2 blocks/CU won't co-schedule.
__global__ __launch_bounds__(512, 4) void gates_lstm_mfma(
    const _Float16* __restrict__ emb_hi, const _Float16* __restrict__ emb_lo,
    const _Float16* __restrict__ h_hi,   const _Float16* __restrict__ h_lo,
    const _Float16* __restrict__ Wg_hi,  const _Float16* __restrict__ Wg_lo,
    const float* __restrict__ b_ih, const float* __restrict__ b_hh,
    float* __restrict__ c,
    _Float16* __restrict__ ho_hi, _Float16* __restrict__ ho_lo) {
  __shared__ __align__(16) _Float16 Ah[4][128][8], Al[4][128][8],
                                    Bh[4][128][8], Bl[4][128][8];   // 32 KB
  const int t    = threadIdx.x;
  const int m0   = blockIdx.x * 128;
  const int by   = blockIdx.y;
  const int n0   = by * 128;
  const int r    = t & 127;                    // staging row
  const int q    = t >> 7;                     // k-chunk 0..3
  const int rw   = r & 64;                     // wave-uniform row base
  const int lane = t & 63, wid = t >> 6;       // 8 waves
  const int wm   = (wid >> 1) * 32;            // 4 M-waves x 32 rows
  const int wn   = wid & 1;                    // 2 N-waves x 64 cols
  const int lc   = lane & 15, lg = lane >> 4;

  auto stage = [&](int k0) {                   // 4 GLL16 per thread
    const _Float16 *pah, *pal;
    if (k0 < kEout) {
      const size_t o = (size_t)(m0 + r) * kEout + k0 + q * 8;
      pah = emb_hi + o; pal = emb_lo + o;
    } else {
      const size_t o = (size_t)(m0 + r) * kH + (k0 - kEout) + q * 8;
      pah = h_hi + o; pal = h_lo + o;
    }
    const size_t ob = (size_t)(n0 + r) * kKg + k0 + q * 8;
    GLL16(pah,        &Ah[q][rw][0]);
    GLL16(pal,        &Al[q][rw][0]);
    GLL16(Wg_hi + ob, &Bh[q][rw][0]);
    GLL16(Wg_lo + ob, &Bl[q][rw][0]);
  };

  f32x4 acc1[2][4] = {}; f32x4 acc2[2][4] = {};
  constexpr int NK = kKg / 32;                 // 40
  for (int ks = 0; ks < NK; ++ks) {
    __syncthreads();                           // prev iter's frag reads complete
    stage(ks * 32);
    __syncthreads();                           // vmcnt(0) drain: tile in LDS
    half8 ah[2], al[2];
#pragma unroll
    for (int mf = 0; mf < 2; ++mf) {
      ah[mf] = *(const half8*)&Ah[lg][wm + mf*16 + lc][0];
      al[mf] = *(const half8*)&Al[lg][wm + mf*16 + lc][0];
    }
#pragma unroll
    for (int nf = 0; nf < 4; ++nf) {
      const half8 bh = *(const half8*)&Bh[lg][wn*64 + nf*16 + lc][0];
      const half8 bl = *(const half8*)&Bl[lg][wn*64 + nf*16 + lc][0];
#pragma unroll
      for (int mf = 0; mf < 2; ++mf) {
        acc1[mf][nf] = __builtin_amdgcn_mfma_f32_16x16x32_f16(ah[mf], bh, acc1[mf][nf], 0, 0, 0);
        acc2[mf][nf] = __builtin_amdgcn_mfma_f32_16x16x32_f16(ah[mf], bl, acc2[mf][nf], 0, 0, 0);
        acc2[mf][nf] = __builtin_amdgcn_mfma_f32_16x16x32_f16(al[mf], bh, acc2[mf][nf], 0, 0, 0);
      }
    }
  }
  // epilogue: lane's column j; 4 n-fragments = 4 gates (i,f,g,o)
  const int j = by * 32 + wn * 16 + lc;
  float bb[4];
#pragma unroll
  for (int nf = 0; nf < 4; ++nf) bb[nf] = b_ih[nf * kH + j] + b_hh[nf * kH + j];
#pragma unroll
  for (int mf = 0; mf < 2; ++mf)
#pragma unroll
    for (int reg = 0; reg < 4; ++reg) {
      const int m = m0 + wm + mf * 16 + lg * 4 + reg;
      const size_t off = (size_t)m * kH + j;
      const float vi = acc1[mf][0][reg] + acc2[mf][0][reg] * kInvLo + bb[0];
      const float vf = acc1[mf][1][reg] + acc2[mf][1][reg] * kInvLo + bb[1];
      const float vg = acc1[mf][2][reg] + acc2[mf][2][reg] * kInvLo + bb[2];
      const float vo = acc1[mf][3][reg] + acc2[mf][3][reg] * kInvLo + bb[3];
      const float cn = sigm(vf) * c[off] + sigm(vi) * tanhf(vg);
      const float hn = sigm(vo) * tanhf(cn);
      c[off] = cn;
      HL s = split2v(hn);
      ho_hi[off] = s.hi; ho_lo[off] = s.lo;
    }
}

// ----------------------------- logits = h @ W_out^T + b (fp16x2 MFMA, 3 passes)
// 64x64 tile, 4 waves (2x2), wave 32x32. Depth-2 counted-vmcnt pipeline;
// staging split by role (waves 0,1 -> A; 2,3 -> B), 4 vmem ops per wave.
__global__ __launch_bounds__(256, 2) void logits_mfma(
    const _Float16* __restrict__ h_hi, const _Float16* __restrict__ h_lo,
    const _Float16* __restrict__ Wo_hi, const _Float16* __restrict__ Wo_lo,
    const float* __restrict__ b_out, float* __restrict__ out) {
  __shared__ __align__(16) _Float16 Ah[2][4][64][8], Al[2][4][64][8],
                                    Bh[2][4][64][8], Bl[2][4][64][8];
  const int t    = threadIdx.x;
  const int m0   = blockIdx.x * 64, n0 = blockIdx.y * 64;
  const int lane = t & 63, wid = t >> 6;
  const int lc   = lane & 15, lg = lane >> 4;
  const int wr   = wid >> 1, wc = wid & 1;    // wave tile 32x32
  const int isB  = wid >> 1;                  // staging role
  const int kq   = (wid & 1) * 2;             // kchunk base

  auto stage = [&](int p, int k0) {           // 4 vmem ops per wave
    if (isB == 0) {
      const size_t o = (size_t)(m0 + lane) * kH + k0 + kq * 8;
      GLL16(h_hi + o,      &Ah[p][kq  ][0][0]);
      GLL16(h_hi + o + 8,  &Ah[p][kq+1][0][0]);
      GLL16(h_lo + o,      &Al[p][kq  ][0][0]);
      GLL16(h_lo + o + 8,  &Al[p][kq+1][0][0]);
    } else {
      const size_t o = (size_t)(n0 + lane) * kH + k0 + kq * 8;
      GLL16(Wo_hi + o,     &Bh[p][kq  ][0][0]);
      GLL16(Wo_hi + o + 8, &Bh[p][kq+1][0][0]);
      GLL16(Wo_lo + o,     &Bl[p][kq  ][0][0]);
      GLL16(Wo_lo + o + 8, &Bl[p][kq+1][0][0]);
    }
  };

  f32x4 acc1[2][2] = {}; f32x4 acc2[2][2] = {};
  constexpr int NK = kH / 32;                 // 32
  stage(0, 0);
  for (int ks = 0; ks < NK; ++ks) {
    const int cur = ks & 1;
    if (ks + 1 < NK) {
      stage(cur ^ 1, (ks + 1) * 32);
      SCHEDB();
      asm volatile("s_waitcnt vmcnt(4)");
    } else {
      SCHEDB();
      asm volatile("s_waitcnt vmcnt(0)");
    }
    SCHEDB();
    __builtin_amdgcn_s_barrier();
    SCHEDB();
    half8 ah[2], al[2], bh[2], bl[2];
#pragma unroll
    for (int mf = 0; mf < 2; ++mf) {
      ah[mf] = *(const half8*)&Ah[cur][lg][wr*32 + mf*16 + lc][0];
      al[mf] = *(const half8*)&Al[cur][lg][wr*32 + mf*16 + lc][0];
    }
#pragma unroll
    for (int nf = 0; nf < 2; ++nf) {
      bh[nf] = *(const half8*)&Bh[cur][lg][wc*32 + nf*16 + lc][0];
      bl[nf] = *(const half8*)&Bl[cur][lg][wc*32 + nf*16 + lc][0];
    }
#pragma unroll
    for (int mf = 0; mf < 2; ++mf)
#pragma unroll
      for (int nf = 0; nf < 2; ++nf) {
        acc1[mf][nf] = __builtin_amdgcn_mfma_f32_16x16x32_f16(ah[mf], bh[nf], acc1[mf][nf], 0, 0, 0);
        acc2[mf][nf] = __builtin_amdgcn_mfma_f32_16x16x32_f16(ah[mf], bl[nf], acc2[mf][nf], 0, 0, 0);
        acc2[mf][nf] = __builtin_amdgcn_mfma_f32_16x16x32_f16(al[mf], bh[nf], acc2[mf][nf], 0, 0, 0);
      }
    SCHEDB();
    __builtin_amdgcn_s_barrier();
  }
#pragma unroll
  for (int mf = 0; mf < 2; ++mf)
#pragma unroll
    for (int reg = 0; reg < 4; ++reg) {
      const int m = m0 + wr*32 + mf * 16 + lg * 4 + reg;
#pragma unroll
      for (int nf = 0; nf < 2; ++nf) {
        const int n = n0 + wc*32 + nf * 16 + lc;
        out[(size_t)m * (kL * kV) + n] = acc1[mf][nf][reg] + acc2[mf][nf][reg] * kInvLo + b_out[n];
      }
    }
}

// --------------------------------- argmax (first-max) + seq write + emb gather
__global__ __launch_bounds__(256) void argmax_gather(const float* __restrict__ logits_t,
                                                     float* __restrict__ seq,
                                                     const _Float16* __restrict__ oemb_hi,
                                                     const _Float16* __restrict__ oemb_lo,
                                                     _Float16* __restrict__ emb_hi,
                                                     _Float16* __restrict__ emb_lo,
                                                     int t) {
  const int lane = threadIdx.x & 63;
  const int wv   = threadIdx.x >> 6;
  const int b    = blockIdx.x * 4 + wv;
  const float* row = logits_t + (size_t)b * (kL * kV);
  float m = -3.4e38f;
  int  mi = 0;
#pragma unroll
  for (int jr = 0; jr < kV / 64; ++jr) {
    const int idx = jr * 64 + lane;
    const float v = row[idx];
    if (v > m) { m = v; mi = idx; }
  }
#pragma unroll
  for (int off = 32; off > 0; off >>= 1) {
    const float om = __shfl_down(m, off);
    const int   oi = __shfl_down(mi, off);
    if (om > m || (om == m && oi < mi)) { m = om; mi = oi; }
  }
  mi = __shfl(mi, 0);
  if (lane == 0) seq[(size_t)b * kL + t] = (float)mi;
  const half4 eh = *(const half4*)&oemb_hi[(size_t)mi * kEout + lane * 4];
  const half4 el = *(const half4*)&oemb_lo[(size_t)mi * kEout + lane * 4];
  *(half4*)&emb_hi[(size_t)b * kEout + lane * 4] = eh;
  *(half4*)&emb_lo[(size_t)b * kEout + lane * 4] = el;
}

// ---------------------------------------------------------------------------
extern "C" void kernel_launch(void* const* d_in, const int* in_sizes, int n_in,
                              void* d_out, int out_size, void* d_ws, size_t ws_size,
                              hipStream_t stream) {
  const int*   x       = (const int*)d_in[0];
  const float* in_emb  = (const float*)d_in[1];
  const float* out_emb = (const float*)d_in[2];
  const float* W_in    = (const float*)d_in[3];
  const float* b_in    = (const float*)d_in[4];
  const float* W_ih    = (const float*)d_in[5];
  const float* b_ih    = (const float*)d_in[6];
  const float* W_hh    = (const float*)d_in[7];
  const float* b_hh    = (const float*)d_in[8];
  const float* W_out   = (const float*)d_in[9];
  const float* b_out   = (const float*)d_in[10];
  const float* sos     = (const float*)d_in[11];

  // workspace layout
  float* cb = (float*)d_ws;                            // [B,H] fp32 cell state
  _Float16* hp = (_Float16*)(cb + (size_t)kB * kH);
  const size_t nBH = (size_t)kB * kH;                  // 2097152
  _Float16* hA_hi  = hp;            _Float16* hA_lo  = hp + nBH;
  _Float16* hB_hi  = hp + 2*nBH;    _Float16* hB_lo  = hp + 3*nBH;
  _Float16* emb_hi = hp + 4*nBH;    _Float16* emb_lo = emb_hi + (size_t)kB*kEout;
  _Float16* Wg_hi  = emb_lo + (size_t)kB*kEout;
  _Float16* Wg_lo  = Wg_hi + (size_t)4*kH*kKg;         // 5242880 each
  _Float16* Wo_hi  = Wg_lo + (size_t)4*kH*kKg;
  _Float16* Wo_lo  = Wo_hi + (size_t)kV*kH;
  _Float16* oe_hi  = Wo_lo + (size_t)kV*kH;
  _Float16* oe_lo  = oe_hi + (size_t)kV*kEout;

  float* seq    = (float*)d_out;                       // [B,L]
  float* logits = seq + (size_t)kB * kL;               // [B,L,V]

  init_state<<<(kB * kH) / 256, 256, 0, stream>>>(cb, emb_hi, emb_lo, sos);
  split_gates_w<<<4 * kH, 320, 0, stream>>>(W_ih, W_hh, Wg_hi, Wg_lo);
  split_plain<<<(kV * kH / 4) / 256, 256, 0, stream>>>(W_out, Wo_hi, Wo_lo, kV * kH / 4);
  split_plain<<<(kV * kEout / 4) / 256, 256, 0, stream>>>(out_emb, oe_hi, oe_lo, kV * kEout / 4);
  h0_gemm<<<dim3(kB / 128, kH / 128), 256, 0, stream>>>(x, in_emb, W_in, b_in, hA_hi, hA_lo);

  for (int t = 0; t < kL; ++t) {
    const _Float16* hi_h = (t & 1) ? hB_hi : hA_hi;
    const _Float16* hi_l = (t & 1) ? hB_lo : hA_lo;
    _Float16* ho_h = (t & 1) ? hA_hi : hB_hi;
    _Float16* ho_l = (t & 1) ? hA_lo : hB_lo;
    gates_lstm_mfma<<<dim3(kB / 128, (4 * kH) / 128), 512, 0, stream>>>(
        emb_hi, emb_lo, hi_h, hi_l, Wg_hi, Wg_lo, b_ih, b_hh, cb, ho_h, ho_l);
    logits_mfma<<<dim3(kB / 64, kV / 64), 256, 0, stream>>>(
        ho_h, ho_l, Wo_hi, Wo_lo, b_out, logits + (size_t)t * kV);
    argmax_gather<<<kB / 4, 256, 0, stream>>>(logits + (size_t)t * kV, seq,
                                              oe_hi, oe_lo, emb_hi, emb_lo, t);
  }
}

// Round 9
// 2008.373 us; speedup vs baseline: 1.3719x; 1.3414x over previous
//
#include <hip/hip_runtime.h>
#include <math.h>

// Problem constants
constexpr int kB    = 2048;
constexpr int kA    = 8;
constexpr int kEin  = 64;
constexpr int kEout = 256;
constexpr int kH    = 1024;
constexpr int kV    = 1024;
constexpr int kL    = 16;
constexpr int kKin  = kA * kEin;      // 512
constexpr int kKg   = kEout + kH;     // 1280
constexpr int kNG   = 4 * kH;         // 4096 gate cols
constexpr float kInvLo = 1.0f / 2048.0f;

using half8 = __attribute__((ext_vector_type(8))) _Float16;
using half4 = __attribute__((ext_vector_type(4))) _Float16;
using f32x4 = __attribute__((ext_vector_type(4))) float;

// async global->LDS, 16B per lane; lds base must be wave-uniform, dest = base + lane*16
#define GLL16(g, l) __builtin_amdgcn_global_load_lds(                        \
    (const __attribute__((address_space(1))) void*)(g),                      \
    (__attribute__((address_space(3))) void*)(l), 16, 0, 0)
#define SCHEDB() __builtin_amdgcn_sched_barrier(0)

__device__ __forceinline__ float sigm(float x) { return 1.0f / (1.0f + expf(-x)); }

// fp32 -> fp16 hi + fp16 lo (x ~= hi + lo/2048), ~22 significant bits
struct HL { _Float16 hi, lo; };
__device__ __forceinline__ HL split2v(float x) {
  HL r;
  r.hi = (_Float16)x;
  r.lo = (_Float16)((x - (float)r.hi) * 2048.0f);
  return r;
}

// ---------------------------------------------------------------- init state
__global__ __launch_bounds__(256) void init_state(float* __restrict__ c,
                                                  int* __restrict__ sym) {
  int i = blockIdx.x * 256 + threadIdx.x;
  c[i] = 0.0f;
  if (i < kB) sym[i] = kV;              // row kV of Eg = SOS row
}

// -------------------------------------------------- plain fp32 -> hi/lo split
__global__ __launch_bounds__(256) void split_plain(const float* __restrict__ src,
                                                   _Float16* __restrict__ hi,
                                                   _Float16* __restrict__ lo,
                                                   int n4) {
  int i = blockIdx.x * 256 + threadIdx.x;
  if (i >= n4) return;
  float4 v = ((const float4*)src)[i];
  half4 h, l;
  HL s0 = split2v(v.x), s1 = split2v(v.y), s2 = split2v(v.z), s3 = split2v(v.w);
  h.x = s0.hi; l.x = s0.lo; h.y = s1.hi; l.y = s1.lo;
  h.z = s2.hi; l.z = s2.lo; h.w = s3.hi; l.w = s3.lo;
  *(half4*)(hi + (size_t)i * 4) = h;
  *(half4*)(lo + (size_t)i * 4) = l;
}

// ------------------------- gates weights: concat [W_ih|W_hh], gate-permute, split
// output row n <-> gate=(n>>4)&3, j=((n>>6)<<4)|(n&15); source row = gate*1024+j
__global__ __launch_bounds__(320) void split_gates_w(const float* __restrict__ W_ih,
                                                     const float* __restrict__ W_hh,
                                                     _Float16* __restrict__ hi,
                                                     _Float16* __restrict__ lo) {
  const int n  = blockIdx.x;
  const int k4 = threadIdx.x * 4;
  const int g  = (n >> 4) & 3;
  const int j  = ((n >> 6) << 4) | (n & 15);
  const int src = g * kH + j;
  float4 v = (k4 < kEout) ? *(const float4*)&W_ih[(size_t)src * kEout + k4]
                          : *(const float4*)&W_hh[(size_t)src * kH + (k4 - kEout)];
  half4 h, l;
  HL s0 = split2v(v.x), s1 = split2v(v.y), s2 = split2v(v.z), s3 = split2v(v.w);
  h.x = s0.hi; l.x = s0.lo; h.y = s1.hi; l.y = s1.lo;
  h.z = s2.hi; l.z = s2.lo; h.w = s3.hi; l.w = s3.lo;
  *(half4*)(hi + (size_t)n * kKg + k4) = h;
  *(half4*)(lo + (size_t)n * kKg + k4) = l;
}

// ------------------------------------------------------- h0 = embed @ W_in^T
// fp32 vector GEMM (runs once); epilogue emits split h0
__global__ __launch_bounds__(256) void h0_gemm(const int* __restrict__ x,
                                               const float* __restrict__ in_emb,
                                               const float* __restrict__ W_in,
                                               const float* __restrict__ b_in,
                                               _Float16* __restrict__ h_hi,
                                               _Float16* __restrict__ h_lo) {
  __shared__ float As[16][128];
  __shared__ float Bs[16][128];
  const int t  = threadIdx.x;
  const int tx = t & 15, ty = t >> 4;
  const int r  = t >> 1;
  const int kc = (t & 1) * 8;
  const int m0 = blockIdx.x * 128;
  const int n0 = blockIdx.y * 128;
  float acc[8][8] = {};
  for (int k0 = 0; k0 < kKin; k0 += 16) {
    const int kk   = k0 + kc;
    const int attr = kk >> 6;
    const int e    = kk & 63;
    const int idx  = x[(m0 + r) * kA + attr];
    const float* pa = in_emb + (size_t)idx * kEin + e;
    float4 a0 = *(const float4*)pa;
    float4 a1 = *(const float4*)(pa + 4);
    const float* pb = W_in + (size_t)(n0 + r) * kKin + kk;
    float4 b0 = *(const float4*)pb;
    float4 b1 = *(const float4*)(pb + 4);
    __syncthreads();
    As[kc+0][r]=a0.x; As[kc+1][r]=a0.y; As[kc+2][r]=a0.z; As[kc+3][r]=a0.w;
    As[kc+4][r]=a1.x; As[kc+5][r]=a1.y; As[kc+6][r]=a1.z; As[kc+7][r]=a1.w;
    Bs[kc+0][r]=b0.x; Bs[kc+1][r]=b0.y; Bs[kc+2][r]=b0.z; Bs[kc+3][r]=b0.w;
    Bs[kc+4][r]=b1.x; Bs[kc+5][r]=b1.y; Bs[kc+6][r]=b1.z; Bs[kc+7][r]=b1.w;
    __syncthreads();
#pragma unroll
    for (int k = 0; k < 16; ++k) {
      float a[8], b[8];
      *(float4*)&a[0] = *(const float4*)&As[k][ty*8];
      *(float4*)&a[4] = *(const float4*)&As[k][ty*8+4];
      *(float4*)&b[0] = *(const float4*)&Bs[k][tx*8];
      *(float4*)&b[4] = *(const float4*)&Bs[k][tx*8+4];
#pragma unroll
      for (int i = 0; i < 8; ++i)
#pragma unroll
        for (int j = 0; j < 8; ++j)
          acc[i][j] = fmaf(a[i], b[j], acc[i][j]);
    }
  }
#pragma unroll
  for (int i = 0; i < 8; ++i) {
    const int gm = m0 + ty*8 + i;
#pragma unroll
    for (int j = 0; j < 8; ++j) {
      const int gn = n0 + tx*8 + j;
      HL s = split2v(acc[i][j] + b_in[gn]);
      h_hi[(size_t)gm * kH + gn] = s.hi;
      h_lo[(size_t)gm * kH + gn] = s.lo;
    }
  }
}

// ------------- Eg = out_emb @ (W_ih gate-permuted)^T, fp16x2 3-pass, one-time.
// M=1024 (vocab), N=4096 (gate-permuted cols), K=256. r4 gates structure.
__global__ __launch_bounds__(256, 2) void eg_gemm(
    const _Float16* __restrict__ oe_hi, const _Float16* __restrict__ oe_lo,
    const _Float16* __restrict__ Wg_hi, const _Float16* __restrict__ Wg_lo,
    float* __restrict__ Eg) {
  __shared__ __align__(16) _Float16 Ah[4][128][8], Al[4][128][8],
                                    Bh[4][128][8], Bl[4][128][8];
  const int t    = threadIdx.x;
  const int m0   = blockIdx.x * 128;
  const int by   = blockIdx.y;
  const int n0   = by * 128;
  const int r    = t & 127, q = t >> 7;
  const int rw   = r & 64;
  const int lane = t & 63, wid = t >> 6;
  const int wm   = (wid >> 1) * 64;
  const int wnv  = wid & 1;
  const int lc   = lane & 15, lg = lane >> 4;
  f32x4 acc1[4][4] = {}; f32x4 acc2[4][4] = {};
  for (int k0 = 0; k0 < kEout; k0 += 32) {
    const size_t oa = (size_t)(m0 + r) * kEout + k0 + q * 16;
    const size_t ob = (size_t)(n0 + r) * kKg + k0 + q * 16;
    __syncthreads();
    GLL16(oe_hi + oa,     &Ah[2*q  ][rw][0]);
    GLL16(oe_hi + oa + 8, &Ah[2*q+1][rw][0]);
    GLL16(oe_lo + oa,     &Al[2*q  ][rw][0]);
    GLL16(oe_lo + oa + 8, &Al[2*q+1][rw][0]);
    GLL16(Wg_hi + ob,     &Bh[2*q  ][rw][0]);
    GLL16(Wg_hi + ob + 8, &Bh[2*q+1][rw][0]);
    GLL16(Wg_lo + ob,     &Bl[2*q  ][rw][0]);
    GLL16(Wg_lo + ob + 8, &Bl[2*q+1][rw][0]);
    __syncthreads();
    half8 ah[4], al[4], bh[4], bl[4];
#pragma unroll
    for (int mf = 0; mf < 4; ++mf) {
      ah[mf] = *(const half8*)&Ah[lg][wm + mf*16 + lc][0];
      al[mf] = *(const half8*)&Al[lg][wm + mf*16 + lc][0];
    }
#pragma unroll
    for (int nf = 0; nf < 4; ++nf) {
      bh[nf] = *(const half8*)&Bh[lg][wnv*64 + nf*16 + lc][0];
      bl[nf] = *(const half8*)&Bl[lg][wnv*64 + nf*16 + lc][0];
    }
#pragma unroll
    for (int mf = 0; mf < 4; ++mf)
#pragma unroll
      for (int nf = 0; nf < 4; ++nf) {
        acc1[mf][nf] = __builtin_amdgcn_mfma_f32_16x16x32_f16(ah[mf], bh[nf], acc1[mf][nf], 0, 0, 0);
        acc2[mf][nf] = __builtin_amdgcn_mfma_f32_16x16x32_f16(ah[mf], bl[nf], acc2[mf][nf], 0, 0, 0);
        acc2[mf][nf] = __builtin_amdgcn_mfma_f32_16x16x32_f16(al[mf], bh[nf], acc2[mf][nf], 0, 0, 0);
      }
  }
#pragma unroll
  for (int mf = 0; mf < 4; ++mf)
#pragma unroll
    for (int reg = 0; reg < 4; ++reg) {
      const int m = m0 + wm + mf * 16 + lg * 4 + reg;
#pragma unroll
      for (int nf = 0; nf < 4; ++nf)
        Eg[(size_t)m * kNG + n0 + wnv*64 + nf*16 + lc] =
            acc1[mf][nf][reg] + acc2[mf][nf][reg] * kInvLo;
    }
}

// ----------------- Eg row kV = sos @ W_ih^T (gate-permuted cols), exact fp32
__global__ __launch_bounds__(256) void gs_row(const float* __restrict__ sos,
                                              const float* __restrict__ W_ih,
                                              float* __restrict__ Eg) {
  const int n = blockIdx.x * 256 + threadIdx.x;   // 0..4095
  const int g = (n >> 4) & 3;
  const int j = ((n >> 6) << 4) | (n & 15);
  const float* w = W_ih + (size_t)(g * kH + j) * kEout;
  float s = 0.0f;
#pragma unroll 4
  for (int k = 0; k < kEout; k += 4) {
    float4 wv = *(const float4*)&w[k];
    float4 sv = *(const float4*)&sos[k];
    s += wv.x*sv.x + wv.y*sv.y + wv.z*sv.z + wv.w*sv.w;
  }
  Eg[(size_t)kV * kNG + n] = s;
}

// --------------------- gates GEMM (fp16x2 MFMA, 3 passes) + fused LSTM pointwise
// K reduced to 1024 (h only); the embedding contribution Eg[sym[m]][n'] is a
// precomputed fp32 gather added in the epilogue. r4 structure: 128x128 tile,
// 4 waves 2x2, wave 64x64, single-buffered, 2 barriers/K-step.
__global__ __launch_bounds__(256, 2) void gates_lstm_mfma(
    const _Float16* __restrict__ h_hi,   const _Float16* __restrict__ h_lo,
    const _Float16* __restrict__ Wg_hi,  const _Float16* __restrict__ Wg_lo,
    const float* __restrict__ Eg,        const int* __restrict__ sym,
    const float* __restrict__ b_ih, const float* __restrict__ b_hh,
    float* __restrict__ c,
    _Float16* __restrict__ ho_hi, _Float16* __restrict__ ho_lo) {
  __shared__ __align__(16) _Float16 Ah[4][128][8], Al[4][128][8],
                                    Bh[4][128][8], Bl[4][128][8];
  __shared__ int syms[128];
  const int t    = threadIdx.x;
  const int m0   = blockIdx.x * 128;
  const int by   = blockIdx.y;
  const int n0   = by * 128;
  const int r    = t & 127, q = t >> 7;       // staging: row, k-half
  const int rw   = r & 64;                    // wave-uniform row base
  const int lane = t & 63,  wid = t >> 6;
  const int wm   = (wid >> 1) * 64;           // wave m offset
  const int wnv  = wid & 1;                   // wave n index
  const int lc   = lane & 15, lg = lane >> 4;

  if (t < 128) syms[t] = sym[m0 + t];

  f32x4 acc1[4][4] = {}; f32x4 acc2[4][4] = {};
  for (int k0 = 0; k0 < kH; k0 += 32) {
    const size_t oa = (size_t)(m0 + r) * kH + k0 + q * 16;
    const size_t ob = (size_t)(n0 + r) * kKg + kEout + k0 + q * 16;
    __syncthreads();                 // previous iter's fragment reads complete
    GLL16(h_hi + oa,     &Ah[2*q  ][rw][0]);
    GLL16(h_hi + oa + 8, &Ah[2*q+1][rw][0]);
    GLL16(h_lo + oa,     &Al[2*q  ][rw][0]);
    GLL16(h_lo + oa + 8, &Al[2*q+1][rw][0]);
    GLL16(Wg_hi + ob,     &Bh[2*q  ][rw][0]);
    GLL16(Wg_hi + ob + 8, &Bh[2*q+1][rw][0]);
    GLL16(Wg_lo + ob,     &Bl[2*q  ][rw][0]);
    GLL16(Wg_lo + ob + 8, &Bl[2*q+1][rw][0]);
    __syncthreads();                 // vmcnt(0) drain -> tile in LDS
    half8 ah[4], al[4], bh[4], bl[4];
#pragma unroll
    for (int mf = 0; mf < 4; ++mf) {
      ah[mf] = *(const half8*)&Ah[lg][wm + mf*16 + lc][0];
      al[mf] = *(const half8*)&Al[lg][wm + mf*16 + lc][0];
    }
#pragma unroll
    for (int nf = 0; nf < 4; ++nf) {
      bh[nf] = *(const half8*)&Bh[lg][wnv*64 + nf*16 + lc][0];
      bl[nf] = *(const half8*)&Bl[lg][wnv*64 + nf*16 + lc][0];
    }
#pragma unroll
    for (int mf = 0; mf < 4; ++mf)
#pragma unroll
      for (int nf = 0; nf < 4; ++nf) {
        acc1[mf][nf] = __builtin_amdgcn_mfma_f32_16x16x32_f16(ah[mf], bh[nf], acc1[mf][nf], 0, 0, 0);
        acc2[mf][nf] = __builtin_amdgcn_mfma_f32_16x16x32_f16(ah[mf], bl[nf], acc2[mf][nf], 0, 0, 0);
        acc2[mf][nf] = __builtin_amdgcn_mfma_f32_16x16x32_f16(al[mf], bh[nf], acc2[mf][nf], 0, 0, 0);
      }
  }
  // epilogue: col j = by*32+wnv*16+lc, 4 n-frags = 4 gates; + Eg[sym][n'] gather
  const int j = by * 32 + wnv * 16 + lc;
  const int nbase = n0 + wnv * 64 + lc;       // Eg col for nf: nbase + nf*16
  float bb[4];
#pragma unroll
  for (int nf = 0; nf < 4; ++nf) bb[nf] = b_ih[nf * kH + j] + b_hh[nf * kH + j];
#pragma unroll
  for (int mf = 0; mf < 4; ++mf)
#pragma unroll
    for (int reg = 0; reg < 4; ++reg) {
      const int lr = wm + mf * 16 + lg * 4 + reg;   // local row
      const int m  = m0 + lr;
      const size_t off = (size_t)m * kH + j;
      const float* Erow = Eg + (size_t)syms[lr] * kNG + nbase;
      const float vi = acc1[mf][0][reg] + acc2[mf][0][reg] * kInvLo + bb[0] + Erow[0];
      const float vf = acc1[mf][1][reg] + acc2[mf][1][reg] * kInvLo + bb[1] + Erow[16];
      const float vg = acc1[mf][2][reg] + acc2[mf][2][reg] * kInvLo + bb[2] + Erow[32];
      const float vo = acc1[mf][3][reg] + acc2[mf][3][reg] * kInvLo + bb[3] + Erow[48];
      const float cn = sigm(vf) * c[off] + sigm(vi) * tanhf(vg);
      const float hn = sigm(vo) * tanhf(cn);
      c[off] = cn;
      HL s = split2v(hn);
      ho_hi[off] = s.hi; ho_lo[off] = s.lo;
    }
}

// ----------------------------- logits = h @ W_out^T + b (fp16x2 MFMA, 3 passes)
// 64x64 tile, 4 waves (2x2), wave 32x32. Depth-2 counted-vmcnt pipeline;
// staging split by role (waves 0,1 -> A; 2,3 -> B), 4 vmem ops per wave.
__global__ __launch_bounds__(256, 2) void logits_mfma(
    const _Float16* __restrict__ h_hi, const _Float16* __restrict__ h_lo,
    const _Float16* __restrict__ Wo_hi, const _Float16* __restrict__ Wo_lo,
    const float* __restrict__ b_out, float* __restrict__ out) {
  __shared__ __align__(16) _Float16 Ah[2][4][64][8], Al[2][4][64][8],
                                    Bh[2][4][64][8], Bl[2][4][64][8];
  const int t    = threadIdx.x;
  const int m0   = blockIdx.x * 64, n0 = blockIdx.y * 64;
  const int lane = t & 63, wid = t >> 6;
  const int lc   = lane & 15, lg = lane >> 4;
  const int wr   = wid >> 1, wc = wid & 1;    // wave tile 32x32
  const int isB  = wid >> 1;                  // staging role
  const int kq   = (wid & 1) * 2;             // kchunk base

  auto stage = [&](int p, int k0) {           // 4 vmem ops per wave
    if (isB == 0) {
      const size_t o = (size_t)(m0 + lane) * kH + k0 + kq * 8;
      GLL16(h_hi + o,      &Ah[p][kq  ][0][0]);
      GLL16(h_hi + o + 8,  &Ah[p][kq+1][0][0]);
      GLL16(h_lo + o,      &Al[p][kq  ][0][0]);
      GLL16(h_lo + o + 8,  &Al[p][kq+1][0][0]);
    } else {
      const size_t o = (size_t)(n0 + lane) * kH + k0 + kq * 8;
      GLL16(Wo_hi + o,     &Bh[p][kq  ][0][0]);
      GLL16(Wo_hi + o + 8, &Bh[p][kq+1][0][0]);
      GLL16(Wo_lo + o,     &Bl[p][kq  ][0][0]);
      GLL16(Wo_lo + o + 8, &Bl[p][kq+1][0][0]);
    }
  };

  f32x4 acc1[2][2] = {}; f32x4 acc2[2][2] = {};
  constexpr int NK = kH / 32;                 // 32
  stage(0, 0);
  for (int ks = 0; ks < NK; ++ks) {
    const int cur = ks & 1;
    if (ks + 1 < NK) {
      stage(cur ^ 1, (ks + 1) * 32);
      SCHEDB();
      asm volatile("s_waitcnt vmcnt(4)");
    } else {
      SCHEDB();
      asm volatile("s_waitcnt vmcnt(0)");
    }
    SCHEDB();
    __builtin_amdgcn_s_barrier();
    SCHEDB();
    half8 ah[2], al[2], bh[2], bl[2];
#pragma unroll
    for (int mf = 0; mf < 2; ++mf) {
      ah[mf] = *(const half8*)&Ah[cur][lg][wr*32 + mf*16 + lc][0];
      al[mf] = *(const half8*)&Al[cur][lg][wr*32 + mf*16 + lc][0];
    }
#pragma unroll
    for (int nf = 0; nf < 2; ++nf) {
      bh[nf] = *(const half8*)&Bh[cur][lg][wc*32 + nf*16 + lc][0];
      bl[nf] = *(const half8*)&Bl[cur][lg][wc*32 + nf*16 + lc][0];
    }
#pragma unroll
    for (int mf = 0; mf < 2; ++mf)
#pragma unroll
      for (int nf = 0; nf < 2; ++nf) {
        acc1[mf][nf] = __builtin_amdgcn_mfma_f32_16x16x32_f16(ah[mf], bh[nf], acc1[mf][nf], 0, 0, 0);
        acc2[mf][nf] = __builtin_amdgcn_mfma_f32_16x16x32_f16(ah[mf], bl[nf], acc2[mf][nf], 0, 0, 0);
        acc2[mf][nf] = __builtin_amdgcn_mfma_f32_16x16x32_f16(al[mf], bh[nf], acc2[mf][nf], 0, 0, 0);
      }
    SCHEDB();
    __builtin_amdgcn_s_barrier();
  }
#pragma unroll
  for (int mf = 0; mf < 2; ++mf)
#pragma unroll
    for (int reg = 0; reg < 4; ++reg) {
      const int m = m0 + wr*32 + mf * 16 + lg * 4 + reg;
#pragma unroll
      for (int nf = 0; nf < 2; ++nf) {
        const int n = n0 + wc*32 + nf * 16 + lc;
        out[(size_t)m * (kL * kV) + n] = acc1[mf][nf][reg] + acc2[mf][nf][reg] * kInvLo + b_out[n];
      }
    }
}

// --------------------------------- argmax (first-max) + seq + sym_int update
__global__ __launch_bounds__(256) void argmax_gather(const float* __restrict__ logits_t,
                                                     float* __restrict__ seq,
                                                     int* __restrict__ sym,
                                                     int t) {
  const int lane = threadIdx.x & 63;
  const int wv   = threadIdx.x >> 6;
  const int b    = blockIdx.x * 4 + wv;
  const float* row = logits_t + (size_t)b * (kL * kV);
  float m = -3.4e38f;
  int  mi = 0;
#pragma unroll
  for (int jr = 0; jr < kV / 64; ++jr) {
    const int idx = jr * 64 + lane;
    const float v = row[idx];
    if (v > m) { m = v; mi = idx; }
  }
#pragma unroll
  for (int off = 32; off > 0; off >>= 1) {
    const float om = __shfl_down(m, off);
    const int   oi = __shfl_down(mi, off);
    if (om > m || (om == m && oi < mi)) { m = om; mi = oi; }
  }
  if (lane == 0) {
    seq[(size_t)b * kL + t] = (float)mi;
    sym[b] = mi;
  }
}

// ---------------------------------------------------------------------------
extern "C" void kernel_launch(void* const* d_in, const int* in_sizes, int n_in,
                              void* d_out, int out_size, void* d_ws, size_t ws_size,
                              hipStream_t stream) {
  const int*   x       = (const int*)d_in[0];
  const float* in_emb  = (const float*)d_in[1];
  const float* out_emb = (const float*)d_in[2];
  const float* W_in    = (const float*)d_in[3];
  const float* b_in    = (const float*)d_in[4];
  const float* W_ih    = (const float*)d_in[5];
  const float* b_ih    = (const float*)d_in[6];
  const float* W_hh    = (const float*)d_in[7];
  const float* b_hh    = (const float*)d_in[8];
  const float* W_out   = (const float*)d_in[9];
  const float* b_out   = (const float*)d_in[10];
  const float* sos     = (const float*)d_in[11];

  // workspace layout
  float* cb  = (float*)d_ws;                           // [B,H] fp32 cell state
  float* Eg  = cb + (size_t)kB * kH;                   // [V+1][4096] fp32
  int*   sym = (int*)(Eg + (size_t)(kV + 1) * kNG);    // [B]
  _Float16* hp = (_Float16*)(sym + kB);
  const size_t nBH = (size_t)kB * kH;                  // 2097152
  _Float16* hA_hi  = hp;            _Float16* hA_lo  = hp + nBH;
  _Float16* hB_hi  = hp + 2*nBH;    _Float16* hB_lo  = hp + 3*nBH;
  _Float16* Wg_hi  = hp + 4*nBH;
  _Float16* Wg_lo  = Wg_hi + (size_t)kNG*kKg;          // 5242880 each
  _Float16* Wo_hi  = Wg_lo + (size_t)kNG*kKg;
  _Float16* Wo_lo  = Wo_hi + (size_t)kV*kH;
  _Float16* oe_hi  = Wo_lo + (size_t)kV*kH;
  _Float16* oe_lo  = oe_hi + (size_t)kV*kEout;

  float* seq    = (float*)d_out;                       // [B,L]
  float* logits = seq + (size_t)kB * kL;               // [B,L,V]

  init_state<<<(kB * kH) / 256, 256, 0, stream>>>(cb, sym);
  split_gates_w<<<kNG, 320, 0, stream>>>(W_ih, W_hh, Wg_hi, Wg_lo);
  split_plain<<<(kV * kH / 4) / 256, 256, 0, stream>>>(W_out, Wo_hi, Wo_lo, kV * kH / 4);
  split_plain<<<(kV * kEout / 4) / 256, 256, 0, stream>>>(out_emb, oe_hi, oe_lo, kV * kEout / 4);
  eg_gemm<<<dim3(kV / 128, kNG / 128), 256, 0, stream>>>(oe_hi, oe_lo, Wg_hi, Wg_lo, Eg);
  gs_row<<<kNG / 256, 256, 0, stream>>>(sos, W_ih, Eg);
  h0_gemm<<<dim3(kB / 128, kH / 128), 256, 0, stream>>>(x, in_emb, W_in, b_in, hA_hi, hA_lo);

  for (int t = 0; t < kL; ++t) {
    const _Float16* hi_h = (t & 1) ? hB_hi : hA_hi;
    const _Float16* hi_l = (t & 1) ? hB_lo : hA_lo;
    _Float16* ho_h = (t & 1) ? hA_hi : hB_hi;
    _Float16* ho_l = (t & 1) ? hA_lo : hB_lo;
    gates_lstm_mfma<<<dim3(kB / 128, kNG / 128), 256, 0, stream>>>(
        hi_h, hi_l, Wg_hi, Wg_lo, Eg, sym, b_ih, b_hh, cb, ho_h, ho_l);
    logits_mfma<<<dim3(kB / 64, kV / 64), 256, 0, stream>>>(
        ho_h, ho_l, Wo_hi, Wo_lo, b_out, logits + (size_t)t * kV);
    argmax_gather<<<kB / 4, 256, 0, stream>>>(logits + (size_t)t * kV, seq, sym, t);
  }
}